// Round 5
// baseline (207.765 us; speedup 1.0000x reference)
//
#include <hip/hip_runtime.h>
#include <hip/hip_bf16.h>
#include <stddef.h>
#include <stdint.h>

#define DM    512
#define NHEAD 8
#define DHEAD 64
#define QLEN  1024
#define KLEN  2048
#define MLEN  1024
#define B_SZ  4

typedef __attribute__((ext_vector_type(8))) short short8;
typedef __attribute__((ext_vector_type(8))) unsigned short ushort8;
typedef __attribute__((ext_vector_type(4))) float floatx4;

static __device__ __forceinline__ unsigned short f2bf(float f) {
  unsigned int u = __float_as_uint(f);
  unsigned int r = (u + 0x7FFFu + ((u >> 16) & 1u)) >> 16;
  return (unsigned short)r;
}
static __device__ __forceinline__ float bf2f(unsigned short h) {
  return __uint_as_float(((unsigned int)h) << 16);
}

#define GLOAD_LDS16(gsrc, ldst)                                               \
  __builtin_amdgcn_global_load_lds(                                           \
      (const __attribute__((address_space(1))) unsigned int*)(gsrc),          \
      (__attribute__((address_space(3))) unsigned int*)(ldst), 16, 0, 0)

// ---------------------------------------------------------------------------
// f32 -> bf16 elementwise (8 per thread)
// ---------------------------------------------------------------------------
__global__ __launch_bounds__(256) void k_f32bf16(
    const float* __restrict__ in, unsigned short* __restrict__ out, int n8) {
  int i = blockIdx.x * 256 + threadIdx.x;
  if (i < n8) {
    float4 a = *(const float4*)(in + (size_t)i * 8);
    float4 b = *(const float4*)(in + (size_t)i * 8 + 4);
    ushort8 o;
    o[0] = f2bf(a.x); o[1] = f2bf(a.y); o[2] = f2bf(a.z); o[3] = f2bf(a.w);
    o[4] = f2bf(b.x); o[5] = f2bf(b.y); o[6] = f2bf(b.z); o[7] = f2bf(b.w);
    *(ushort8*)(out + (size_t)i * 8) = o;
  }
}

// ---------------------------------------------------------------------------
// f32 -> (hi, lo) bf16 split
// ---------------------------------------------------------------------------
__global__ __launch_bounds__(256) void k_wosplit(
    const float* __restrict__ in, unsigned short* __restrict__ oh,
    unsigned short* __restrict__ ol, int n8) {
  int i = blockIdx.x * 256 + threadIdx.x;
  if (i < n8) {
    ushort8 vh, vl;
#pragma unroll
    for (int j = 0; j < 8; ++j) {
      float f = in[(size_t)i * 8 + j];
      unsigned short h = f2bf(f);
      vh[j] = h;
      vl[j] = f2bf(f - bf2f(h));
    }
    *(ushort8*)(oh + (size_t)i * 8) = vh;
    *(ushort8*)(ol + (size_t)i * 8) = vl;
  }
}

// ---------------------------------------------------------------------------
// Transpose-convert the 4 projection weights: W[512 k][512 n] f32 ->
// Wt[512 n][512 k] bf16 (4 matrices stacked, stride 262144).
// ---------------------------------------------------------------------------
__global__ __launch_bounds__(256) void k_wtrans(
    const float* __restrict__ W0, const float* __restrict__ W1,
    const float* __restrict__ W2, const float* __restrict__ W3,
    unsigned short* __restrict__ wt) {
  __shared__ float tile[64][65];
  const int z = blockIdx.z;
  const float* W = (z == 0) ? W0 : (z == 1) ? W1 : (z == 2) ? W2 : W3;
  unsigned short* out = wt + (size_t)z * 262144;
  const int tid = threadIdx.x;
  const int row = tid >> 2, c0 = (tid & 3) * 16;
  const int kb = blockIdx.y * 64, nb = blockIdx.x * 64;
#pragma unroll
  for (int j = 0; j < 4; ++j) {
    float4 ld = *(const float4*)(W + (size_t)(kb + row) * DM + nb + c0 + j * 4);
    tile[row][c0 + j * 4 + 0] = ld.x;
    tile[row][c0 + j * 4 + 1] = ld.y;
    tile[row][c0 + j * 4 + 2] = ld.z;
    tile[row][c0 + j * 4 + 3] = ld.w;
  }
  __syncthreads();
  unsigned short ob[16];
#pragma unroll
  for (int j = 0; j < 16; ++j) ob[j] = f2bf(tile[c0 + j][row]);
  unsigned short* orow = out + (size_t)(nb + row) * DM + kb + c0;
  *(ushort8*)(orow) = *(ushort8*)&ob[0];
  *(ushort8*)(orow + 8) = *(ushort8*)&ob[8];
}

// ---------------------------------------------------------------------------
// v_ [B*KLEN][512] bf16 -> vt [b][n][d][KLEN] bf16 (global V transpose)
// ---------------------------------------------------------------------------
__global__ __launch_bounds__(256) void k_vtrans(
    const unsigned short* __restrict__ v_, unsigned short* __restrict__ vt) {
  __shared__ unsigned short tile[64][72];
  const int tid = threadIdx.x;
  const int row = tid >> 2, c0 = (tid & 3) * 16;
  const int kt = blockIdx.x;            // key tile (64 keys)
  const int bn = blockIdx.y;            // b*8+n
  const int bb = bn >> 3, n = bn & 7;
  const unsigned short* src =
      v_ + ((size_t)(bb * KLEN) + kt * 64 + row) * DM + n * DHEAD + c0;
  *(ushort8*)&tile[row][c0] = *(const ushort8*)src;
  *(ushort8*)&tile[row][c0 + 8] = *(const ushort8*)(src + 8);
  __syncthreads();
  // write: d = row, keys c0..c0+15
  unsigned short ob[16];
#pragma unroll
  for (int j = 0; j < 16; ++j) ob[j] = tile[c0 + j][row];
  unsigned short* dst =
      vt + ((size_t)bn * DHEAD + row) * KLEN + kt * 64 + c0;
  *(ushort8*)dst = *(ushort8*)&ob[0];
  *(ushort8*)(dst + 8) = *(ushort8*)&ob[8];
}

// ---------------------------------------------------------------------------
// Fused bf16 MFMA projection GEMM: C[M][512] = A[M][512] * Wt[512][512]^T
// ---------------------------------------------------------------------------
__global__ __launch_bounds__(256) void k_proj_mfma(
    const unsigned short* __restrict__ xb, const unsigned short* __restrict__ pb,
    const unsigned short* __restrict__ wt,
    unsigned short* __restrict__ q_, unsigned short* __restrict__ k_,
    unsigned short* __restrict__ v_, unsigned short* __restrict__ r_) {
  __shared__ unsigned short Abuf[128 * 64];
  __shared__ unsigned short Bbuf[128 * 64];
  const int tid = threadIdx.x, w = tid >> 6, lane = tid & 63;
  const int c = lane & 15, g = lane >> 4;
  const int wr = w >> 1, wc = w & 1;
  const int mb = blockIdx.x, nb = blockIdx.y;
  int prob, mloc;
  const unsigned short* A;
  unsigned short* C;
  if (mb < 32)        { prob = 0; mloc = mb;       A = xb; C = q_; }
  else if (mb < 96)   { prob = 1; mloc = mb - 32;  A = xb; C = k_; }
  else if (mb < 160)  { prob = 2; mloc = mb - 96;  A = xb; C = v_; }
  else                { prob = 3; mloc = mb - 160; A = pb; C = r_; }
  const unsigned short* W = wt + (size_t)prob * 262144;
  const int m0 = mloc * 128;
  const int lrow = lane >> 3, lslot = lane & 7;

  floatx4 acc[4][4];
#pragma unroll
  for (int m = 0; m < 4; ++m)
#pragma unroll
    for (int nn = 0; nn < 4; ++nn) acc[m][nn] = (floatx4){0.f, 0.f, 0.f, 0.f};

  for (int k0 = 0; k0 < DM; k0 += 64) {
    __syncthreads();
#pragma unroll
    for (int iq = 0; iq < 4; ++iq) {
      const int r0 = w * 32 + iq * 8;
      const int arow = r0 + lrow;
      const int mrow = m0 + arow;
      const int grow =
          (prob == 0) ? ((mrow >> 10) * KLEN + (mrow & 1023) + MLEN) : mrow;
      const int sgA = lslot ^ (arow & 7);
      GLOAD_LDS16(A + (size_t)grow * DM + k0 + sgA * 8, Abuf + r0 * 64);
      const int nrow = nb * 128 + arow;
      GLOAD_LDS16(W + (size_t)nrow * DM + k0 + sgA * 8, Bbuf + r0 * 64);
    }
    __syncthreads();
#pragma unroll
    for (int kk = 0; kk < 2; ++kk) {
      short8 af[4], bf[4];
#pragma unroll
      for (int m = 0; m < 4; ++m) {
        const int arow = wr * 64 + m * 16 + c;
        const int slot = (kk * 4 + g) ^ (arow & 7);
        af[m] = *(const short8*)(Abuf + arow * 64 + slot * 8);
      }
#pragma unroll
      for (int nn = 0; nn < 4; ++nn) {
        const int brow = wc * 64 + nn * 16 + c;
        const int slot = (kk * 4 + g) ^ (brow & 7);
        bf[nn] = *(const short8*)(Bbuf + brow * 64 + slot * 8);
      }
#pragma unroll
      for (int m = 0; m < 4; ++m)
#pragma unroll
        for (int nn = 0; nn < 4; ++nn)
          acc[m][nn] = __builtin_amdgcn_mfma_f32_16x16x32_bf16(
              af[m], bf[nn], acc[m][nn], 0, 0, 0);
    }
  }
#pragma unroll
  for (int m = 0; m < 4; ++m)
#pragma unroll
    for (int nn = 0; nn < 4; ++nn)
#pragma unroll
      for (int rg = 0; rg < 4; ++rg) {
        const int row = m0 + wr * 64 + m * 16 + 4 * g + rg;
        const int col = nb * 128 + wc * 64 + nn * 16 + c;
        C[(size_t)row * DM + col] = f2bf(acc[m][nn][rg]);
      }
}

// ---------------------------------------------------------------------------
// out[4096][512] = Ah*Bh^T + Al*Bh^T + Ah*Bl^T   (split-bf16, f32 accum)
// ---------------------------------------------------------------------------
__global__ __launch_bounds__(256) void k_out_mfma(
    const unsigned short* __restrict__ Ah, const unsigned short* __restrict__ Al,
    const unsigned short* __restrict__ Bh, const unsigned short* __restrict__ Bl,
    float* __restrict__ C) {
  __shared__ unsigned short bufAh[64 * 64], bufAl[64 * 64];
  __shared__ unsigned short bufBh[64 * 64], bufBl[64 * 64];
  const int tid = threadIdx.x, w = tid >> 6, lane = tid & 63;
  const int c = lane & 15, g = lane >> 4;
  const int wr = w >> 1, wc = w & 1;
  const int bm = blockIdx.x, bn = blockIdx.y;
  const int lrow = lane >> 3, lslot = lane & 7;
  floatx4 acc[2][2];
#pragma unroll
  for (int mi = 0; mi < 2; ++mi)
#pragma unroll
    for (int ni = 0; ni < 2; ++ni) acc[mi][ni] = (floatx4){0.f, 0.f, 0.f, 0.f};

  for (int k0 = 0; k0 < DM; k0 += 64) {
    __syncthreads();
#pragma unroll
    for (int iq = 0; iq < 2; ++iq) {
      const int r0 = w * 16 + iq * 8;
      const int arow = r0 + lrow;
      const int sg = lslot ^ (arow & 7);
      GLOAD_LDS16(Ah + (size_t)(bm * 64 + arow) * DM + k0 + sg * 8, bufAh + r0 * 64);
      GLOAD_LDS16(Al + (size_t)(bm * 64 + arow) * DM + k0 + sg * 8, bufAl + r0 * 64);
      GLOAD_LDS16(Bh + (size_t)(bn * 64 + arow) * DM + k0 + sg * 8, bufBh + r0 * 64);
      GLOAD_LDS16(Bl + (size_t)(bn * 64 + arow) * DM + k0 + sg * 8, bufBl + r0 * 64);
    }
    __syncthreads();
#pragma unroll
    for (int kk = 0; kk < 2; ++kk) {
      short8 ah[2], al[2], bh[2], bl[2];
#pragma unroll
      for (int mi = 0; mi < 2; ++mi) {
        const int row = wr * 32 + mi * 16 + c;
        const int slot = (kk * 4 + g) ^ (row & 7);
        ah[mi] = *(const short8*)(bufAh + row * 64 + slot * 8);
        al[mi] = *(const short8*)(bufAl + row * 64 + slot * 8);
      }
#pragma unroll
      for (int ni = 0; ni < 2; ++ni) {
        const int row = wc * 32 + ni * 16 + c;
        const int slot = (kk * 4 + g) ^ (row & 7);
        bh[ni] = *(const short8*)(bufBh + row * 64 + slot * 8);
        bl[ni] = *(const short8*)(bufBl + row * 64 + slot * 8);
      }
#pragma unroll
      for (int mi = 0; mi < 2; ++mi)
#pragma unroll
        for (int ni = 0; ni < 2; ++ni) {
          acc[mi][ni] = __builtin_amdgcn_mfma_f32_16x16x32_bf16(
              ah[mi], bh[ni], acc[mi][ni], 0, 0, 0);
          acc[mi][ni] = __builtin_amdgcn_mfma_f32_16x16x32_bf16(
              al[mi], bh[ni], acc[mi][ni], 0, 0, 0);
          acc[mi][ni] = __builtin_amdgcn_mfma_f32_16x16x32_bf16(
              ah[mi], bl[ni], acc[mi][ni], 0, 0, 0);
        }
    }
  }
#pragma unroll
  for (int mi = 0; mi < 2; ++mi)
#pragma unroll
    for (int ni = 0; ni < 2; ++ni)
#pragma unroll
      for (int rg = 0; rg < 4; ++rg) {
        const int row = bm * 64 + wr * 32 + mi * 16 + 4 * g + rg;
        const int col = bn * 64 + wc * 32 + ni * 16 + c;
        C[(size_t)row * DM + col] = acc[mi][ni][rg];
      }
}

// ---------------------------------------------------------------------------
// Flash MFMA attention, BARRIER-FREE main loop. 8 waves (512 thr); wave w:
// qsub = w&3 (16 q rows), half = w>>2 (even/odd key tiles). K, R, V^T all
// loaded direct from global (V pre-transposed in vt); P is wave-private LDS.
// Split-K halves merge through LDS after the loop (only barriers).
// ---------------------------------------------------------------------------
__global__ __launch_bounds__(512, 4) void k_attn_mfma(
    const unsigned short* __restrict__ q, const unsigned short* __restrict__ k,
    const unsigned short* __restrict__ vt, const unsigned short* __restrict__ r,
    const float* __restrict__ bk, const float* __restrict__ br,
    unsigned short* __restrict__ aoh, unsigned short* __restrict__ aol) {
  __shared__ char smix[19968];               // P (in-loop) / combine (post-loop)
  unsigned short (*P)[16][76] = (unsigned short (*)[16][76])smix;  // [8 waves]
  float (*oC)[16][68] = (float (*)[16][68])smix;                   // [4 qsub]
  float* mlC = (float*)(smix + 17408);                             // [4][2][16]

  const int tid = threadIdx.x;
  const int w = tid >> 6;
  const int half = w >> 2;
  const int qsub = w & 3;
  const int lane = tid & 63;
  const int c = lane & 15;
  const int g = lane >> 4;
  const int n = blockIdx.y;
  const int b = blockIdx.z;
  const int grp = (n + NHEAD * b) >> 4;
  const int i0 = (grp ? (15 - (int)blockIdx.x) : (int)blockIdx.x) * 64;
  const int qb = i0 + qsub * 16;
  const unsigned short* vtbn = vt + (size_t)(b * NHEAD + n) * DHEAD * KLEN;

  short8 aqk[2], aqr[2];
  {
    const unsigned short* qrow =
        q + ((size_t)(b * QLEN) + qb + c) * DM + n * DHEAD;
#pragma unroll
    for (int kb2 = 0; kb2 < 2; ++kb2) {
      short8 qv = *(const short8*)(qrow + kb2 * 32 + g * 8);
#pragma unroll
      for (int j = 0; j < 8; ++j) {
        int d = kb2 * 32 + g * 8 + j;
        float f = bf2f((unsigned short)qv[j]);
        aqk[kb2][j] = (short)f2bf((f + bk[n * DHEAD + d]) * 0.125f);
        aqr[kb2][j] = (short)f2bf((f + br[n * DHEAD + d]) * 0.125f);
      }
    }
  }

  floatx4 o[4];
#pragma unroll
  for (int t = 0; t < 4; ++t) o[t] = (floatx4){0.f, 0.f, 0.f, 0.f};
  float m[4], lsum[4];
#pragma unroll
  for (int rg = 0; rg < 4; ++rg) { m[rg] = -1e30f; lsum[rg] = 0.f; }

  const int nkb = i0 / 64 + 17;

  for (int t = half; t < nkb; t += 2) {
    const int j0 = t * 64;
    // BD tiles in regs + shuffle into gathered form
    const int jrbase = j0 - qb + 1008;
    float sh[5][4];
#pragma unroll
    for (int tau5 = 0; tau5 < 5; ++tau5) {
      const int jrow = min(jrbase + tau5 * 16 + c, KLEN - 1);
      const unsigned short* rr = r + (size_t)jrow * DM + n * DHEAD;
      short8 rf0 = *(const short8*)(rr + g * 8);
      short8 rf1 = *(const short8*)(rr + 32 + g * 8);
      floatx4 bd = (floatx4){0.f, 0.f, 0.f, 0.f};
      bd = __builtin_amdgcn_mfma_f32_16x16x32_bf16(aqr[0], rf0, bd, 0, 0, 0);
      bd = __builtin_amdgcn_mfma_f32_16x16x32_bf16(aqr[1], rf1, bd, 0, 0, 0);
#pragma unroll
      for (int rg = 0; rg < 4; ++rg) {
        const int srcl = (g << 4) | ((15 + c - 4 * g - rg) & 15);
        sh[tau5][rg] = __shfl(bd[rg], srcl, 64);
      }
    }

    // AC + gather + mask
    floatx4 s[4];
    const bool lastblk = (t == nkb - 1);
#pragma unroll
    for (int tau = 0; tau < 4; ++tau) {
      const unsigned short* kr =
          k + ((size_t)(b * KLEN) + j0 + tau * 16 + c) * DM + n * DHEAD;
      short8 kf0 = *(const short8*)(kr + g * 8);
      short8 kf1 = *(const short8*)(kr + 32 + g * 8);
      floatx4 acc = (floatx4){0.f, 0.f, 0.f, 0.f};
      acc = __builtin_amdgcn_mfma_f32_16x16x32_bf16(aqk[0], kf0, acc, 0, 0, 0);
      acc = __builtin_amdgcn_mfma_f32_16x16x32_bf16(aqk[1], kf1, acc, 0, 0, 0);
#pragma unroll
      for (int rg = 0; rg < 4; ++rg) {
        const int ql = 4 * g + rg;
        float sv = acc[rg] + ((c > ql) ? sh[tau + 1][rg] : sh[tau][rg]);
        if (lastblk && (tau * 16 + c > qsub * 16 + ql)) sv = -1e30f;
        s[tau][rg] = sv;
      }
    }

    // online softmax
    float fac[4];
#pragma unroll
    for (int rg = 0; rg < 4; ++rg) {
      float mx = fmaxf(fmaxf(s[0][rg], s[1][rg]), fmaxf(s[2][rg], s[3][rg]));
#pragma unroll
      for (int shm = 1; shm < 16; shm <<= 1) mx = fmaxf(mx, __shfl_xor(mx, shm, 64));
      float mn = fmaxf(m[rg], mx);
      fac[rg] = __expf(m[rg] - mn);
      m[rg] = mn;
    }
    float rsum[4] = {0.f, 0.f, 0.f, 0.f};
#pragma unroll
    for (int tau = 0; tau < 4; ++tau) {
#pragma unroll
      for (int rg = 0; rg < 4; ++rg) {
        float p = __expf(s[tau][rg] - m[rg]);
        rsum[rg] += p;
        P[w][4 * g + rg][tau * 16 + c] = f2bf(p);
      }
    }
#pragma unroll
    for (int rg = 0; rg < 4; ++rg) {
      float rs = rsum[rg];
#pragma unroll
      for (int shm = 1; shm < 16; shm <<= 1) rs += __shfl_xor(rs, shm, 64);
      lsum[rg] = lsum[rg] * fac[rg] + rs;
#pragma unroll
      for (int td = 0; td < 4; ++td) o[td][rg] *= fac[rg];
    }

    // PV: P from wave-private LDS, V^T fragments direct from global
    short8 pa0 = *(const short8*)&P[w][c][g * 8];
    short8 pa1 = *(const short8*)&P[w][c][32 + g * 8];
#pragma unroll
    for (int td = 0; td < 4; ++td) {
      const unsigned short* vr = vtbn + (size_t)(td * 16 + c) * KLEN + j0;
      short8 vb0 = *(const short8*)(vr + g * 8);
      short8 vb1 = *(const short8*)(vr + 32 + g * 8);
      o[td] = __builtin_amdgcn_mfma_f32_16x16x32_bf16(pa0, vb0, o[td], 0, 0, 0);
      o[td] = __builtin_amdgcn_mfma_f32_16x16x32_bf16(pa1, vb1, o[td], 0, 0, 0);
    }
  }

  // combine halves
  __syncthreads();
  if (half == 1) {
#pragma unroll
    for (int td = 0; td < 4; ++td)
#pragma unroll
      for (int rg = 0; rg < 4; ++rg)
        oC[qsub][4 * g + rg][td * 16 + c] = o[td][rg];
    if (c == 0) {
#pragma unroll
      for (int rg = 0; rg < 4; ++rg) {
        mlC[(qsub * 2 + 0) * 16 + 4 * g + rg] = m[rg];
        mlC[(qsub * 2 + 1) * 16 + 4 * g + rg] = lsum[rg];
      }
    }
  }
  __syncthreads();
  if (half == 0) {
#pragma unroll
    for (int rg = 0; rg < 4; ++rg) {
      const int ql = 4 * g + rg;
      float m1 = mlC[(qsub * 2 + 0) * 16 + ql];
      float l1 = mlC[(qsub * 2 + 1) * 16 + ql];
      float M = fmaxf(m[rg], m1);
      float w0 = __expf(m[rg] - M);
      float w1 = __expf(m1 - M);
      float invl = 1.0f / (lsum[rg] * w0 + l1 * w1);
#pragma unroll
      for (int td = 0; td < 4; ++td) {
        float val = (o[td][rg] * w0 + oC[qsub][ql][td * 16 + c] * w1) * invl;
        unsigned short hi = f2bf(val);
        float lo = val - bf2f(hi);
        size_t off = ((size_t)(b * QLEN) + qb + ql) * DM + n * DHEAD + td * 16 + c;
        aoh[off] = hi;
        aol[off] = f2bf(lo);
      }
    }
  }
}

// ---------------------------------------------------------------------------
extern "C" void kernel_launch(void* const* d_in, const int* in_sizes, int n_in,
                              void* d_out, int out_size, void* d_ws, size_t ws_size,
                              hipStream_t stream) {
  const float* x  = (const float*)d_in[0];
  const float* p  = (const float*)d_in[1];
  const float* Wq = (const float*)d_in[2];
  const float* Wk = (const float*)d_in[3];
  const float* Wv = (const float*)d_in[4];
  const float* Wo = (const float*)d_in[5];
  const float* Wp = (const float*)d_in[6];
  const float* bk = (const float*)d_in[7];
  const float* br = (const float*)d_in[8];
  float* out = (float*)d_out;

  unsigned short* q_  = (unsigned short*)d_ws;        // 2M u16
  unsigned short* k_  = q_  + (size_t)2097152;        // 4M
  unsigned short* v_  = k_  + (size_t)4194304;        // 4M
  unsigned short* r_  = v_  + (size_t)4194304;        // 1M
  unsigned short* xb  = r_  + (size_t)1048576;        // 4M
  unsigned short* pb  = xb  + (size_t)4194304;        // 1M
  unsigned short* wt  = pb  + (size_t)1048576;        // 1M
  unsigned short* woh = wt  + (size_t)1048576;        // 256K
  unsigned short* wol = woh + (size_t)262144;         // 256K
  unsigned short* aoh = wol + (size_t)262144;         // 2M
  unsigned short* aol = aoh + (size_t)2097152;        // 2M
  unsigned short* vt_ = aol + (size_t)2097152;        // 4M

  k_f32bf16<<<2048, 256, 0, stream>>>(x, xb, (B_SZ * KLEN * DM) / 8);
  k_f32bf16<<<512, 256, 0, stream>>>(p, pb, (KLEN * DM) / 8);
  k_wtrans<<<dim3(8, 8, 4), 256, 0, stream>>>(Wq, Wk, Wv, Wp, wt);
  k_wosplit<<<128, 256, 0, stream>>>(Wo, woh, wol, (DM * DM) / 8);
  k_proj_mfma<<<dim3(176, 4), 256, 0, stream>>>(xb, pb, wt, q_, k_, v_, r_);
  k_vtrans<<<dim3(KLEN / 64, NHEAD * B_SZ), 256, 0, stream>>>(v_, vt_);
  k_attn_mfma<<<dim3(16, 8, 4), 512, 0, stream>>>(
      q_, k_, vt_, r_, bk, br, aoh, aol);
  k_out_mfma<<<dim3(64, 8), 256, 0, stream>>>(aoh, aol, woh, wol, out);
}

// Round 6
// 138.040 us; speedup vs baseline: 1.5051x; 1.5051x over previous
//
#include <hip/hip_runtime.h>
#include <hip/hip_bf16.h>
#include <stddef.h>
#include <stdint.h>

#define DM    512
#define NHEAD 8
#define DHEAD 64
#define QLEN  1024
#define KLEN  2048
#define MLEN  1024
#define B_SZ  4

typedef __attribute__((ext_vector_type(8))) short short8;
typedef __attribute__((ext_vector_type(8))) unsigned short ushort8;
typedef __attribute__((ext_vector_type(4))) float floatx4;

static __device__ __forceinline__ unsigned short f2bf(float f) {
  unsigned int u = __float_as_uint(f);
  unsigned int r = (u + 0x7FFFu + ((u >> 16) & 1u)) >> 16;
  return (unsigned short)r;
}
static __device__ __forceinline__ float bf2f(unsigned short h) {
  return __uint_as_float(((unsigned int)h) << 16);
}

#define GLOAD_LDS16(gsrc, ldst)                                               \
  __builtin_amdgcn_global_load_lds(                                           \
      (const __attribute__((address_space(1))) unsigned int*)(gsrc),          \
      (__attribute__((address_space(3))) unsigned int*)(ldst), 16, 0, 0)

// ---------------------------------------------------------------------------
// f32 -> bf16 elementwise (8 per thread)
// ---------------------------------------------------------------------------
__global__ __launch_bounds__(256) void k_f32bf16(
    const float* __restrict__ in, unsigned short* __restrict__ out, int n8) {
  int i = blockIdx.x * 256 + threadIdx.x;
  if (i < n8) {
    float4 a = *(const float4*)(in + (size_t)i * 8);
    float4 b = *(const float4*)(in + (size_t)i * 8 + 4);
    ushort8 o;
    o[0] = f2bf(a.x); o[1] = f2bf(a.y); o[2] = f2bf(a.z); o[3] = f2bf(a.w);
    o[4] = f2bf(b.x); o[5] = f2bf(b.y); o[6] = f2bf(b.z); o[7] = f2bf(b.w);
    *(ushort8*)(out + (size_t)i * 8) = o;
  }
}

// ---------------------------------------------------------------------------
// f32 -> (hi, lo) bf16 split
// ---------------------------------------------------------------------------
__global__ __launch_bounds__(256) void k_wosplit(
    const float* __restrict__ in, unsigned short* __restrict__ oh,
    unsigned short* __restrict__ ol, int n8) {
  int i = blockIdx.x * 256 + threadIdx.x;
  if (i < n8) {
    ushort8 vh, vl;
#pragma unroll
    for (int j = 0; j < 8; ++j) {
      float f = in[(size_t)i * 8 + j];
      unsigned short h = f2bf(f);
      vh[j] = h;
      vl[j] = f2bf(f - bf2f(h));
    }
    *(ushort8*)(oh + (size_t)i * 8) = vh;
    *(ushort8*)(ol + (size_t)i * 8) = vl;
  }
}

// ---------------------------------------------------------------------------
// Transpose-convert the 4 projection weights: W[512 k][512 n] f32 ->
// Wt[512 n][512 k] bf16 (4 matrices stacked, stride 262144).
// ---------------------------------------------------------------------------
__global__ __launch_bounds__(256) void k_wtrans(
    const float* __restrict__ W0, const float* __restrict__ W1,
    const float* __restrict__ W2, const float* __restrict__ W3,
    unsigned short* __restrict__ wt) {
  __shared__ float tile[64][65];
  const int z = blockIdx.z;
  const float* W = (z == 0) ? W0 : (z == 1) ? W1 : (z == 2) ? W2 : W3;
  unsigned short* out = wt + (size_t)z * 262144;
  const int tid = threadIdx.x;
  const int row = tid >> 2, c0 = (tid & 3) * 16;
  const int kb = blockIdx.y * 64, nb = blockIdx.x * 64;
#pragma unroll
  for (int j = 0; j < 4; ++j) {
    float4 ld = *(const float4*)(W + (size_t)(kb + row) * DM + nb + c0 + j * 4);
    tile[row][c0 + j * 4 + 0] = ld.x;
    tile[row][c0 + j * 4 + 1] = ld.y;
    tile[row][c0 + j * 4 + 2] = ld.z;
    tile[row][c0 + j * 4 + 3] = ld.w;
  }
  __syncthreads();
  unsigned short ob[16];
#pragma unroll
  for (int j = 0; j < 16; ++j) ob[j] = f2bf(tile[c0 + j][row]);
  unsigned short* orow = out + (size_t)(nb + row) * DM + kb + c0;
  *(ushort8*)(orow) = *(ushort8*)&ob[0];
  *(ushort8*)(orow + 8) = *(ushort8*)&ob[8];
}

// ---------------------------------------------------------------------------
// v_ [B*KLEN][512] bf16 -> vt [b][n][d][KLEN] bf16 (global V transpose)
// ---------------------------------------------------------------------------
__global__ __launch_bounds__(256) void k_vtrans(
    const unsigned short* __restrict__ v_, unsigned short* __restrict__ vt) {
  __shared__ unsigned short tile[64][72];
  const int tid = threadIdx.x;
  const int row = tid >> 2, c0 = (tid & 3) * 16;
  const int kt = blockIdx.x;            // key tile (64 keys)
  const int bn = blockIdx.y;            // b*8+n
  const int bb = bn >> 3, n = bn & 7;
  const unsigned short* src =
      v_ + ((size_t)(bb * KLEN) + kt * 64 + row) * DM + n * DHEAD + c0;
  *(ushort8*)&tile[row][c0] = *(const ushort8*)src;
  *(ushort8*)&tile[row][c0 + 8] = *(const ushort8*)(src + 8);
  __syncthreads();
  unsigned short ob[16];
#pragma unroll
  for (int j = 0; j < 16; ++j) ob[j] = tile[c0 + j][row];
  unsigned short* dst =
      vt + ((size_t)bn * DHEAD + row) * KLEN + kt * 64 + c0;
  *(ushort8*)dst = *(ushort8*)&ob[0];
  *(ushort8*)(dst + 8) = *(ushort8*)&ob[8];
}

// ---------------------------------------------------------------------------
// Fused bf16 MFMA projection GEMM: C[M][512] = A[M][512] * Wt[512][512]^T
// ---------------------------------------------------------------------------
__global__ __launch_bounds__(256) void k_proj_mfma(
    const unsigned short* __restrict__ xb, const unsigned short* __restrict__ pb,
    const unsigned short* __restrict__ wt,
    unsigned short* __restrict__ q_, unsigned short* __restrict__ k_,
    unsigned short* __restrict__ v_, unsigned short* __restrict__ r_) {
  __shared__ unsigned short Abuf[128 * 64];
  __shared__ unsigned short Bbuf[128 * 64];
  const int tid = threadIdx.x, w = tid >> 6, lane = tid & 63;
  const int c = lane & 15, g = lane >> 4;
  const int wr = w >> 1, wc = w & 1;
  const int mb = blockIdx.x, nb = blockIdx.y;
  int prob, mloc;
  const unsigned short* A;
  unsigned short* C;
  if (mb < 32)        { prob = 0; mloc = mb;       A = xb; C = q_; }
  else if (mb < 96)   { prob = 1; mloc = mb - 32;  A = xb; C = k_; }
  else if (mb < 160)  { prob = 2; mloc = mb - 96;  A = xb; C = v_; }
  else                { prob = 3; mloc = mb - 160; A = pb; C = r_; }
  const unsigned short* W = wt + (size_t)prob * 262144;
  const int m0 = mloc * 128;
  const int lrow = lane >> 3, lslot = lane & 7;

  floatx4 acc[4][4];
#pragma unroll
  for (int m = 0; m < 4; ++m)
#pragma unroll
    for (int nn = 0; nn < 4; ++nn) acc[m][nn] = (floatx4){0.f, 0.f, 0.f, 0.f};

  for (int k0 = 0; k0 < DM; k0 += 64) {
    __syncthreads();
#pragma unroll
    for (int iq = 0; iq < 4; ++iq) {
      const int r0 = w * 32 + iq * 8;
      const int arow = r0 + lrow;
      const int mrow = m0 + arow;
      const int grow =
          (prob == 0) ? ((mrow >> 10) * KLEN + (mrow & 1023) + MLEN) : mrow;
      const int sgA = lslot ^ (arow & 7);
      GLOAD_LDS16(A + (size_t)grow * DM + k0 + sgA * 8, Abuf + r0 * 64);
      const int nrow = nb * 128 + arow;
      GLOAD_LDS16(W + (size_t)nrow * DM + k0 + sgA * 8, Bbuf + r0 * 64);
    }
    __syncthreads();
#pragma unroll
    for (int kk = 0; kk < 2; ++kk) {
      short8 af[4], bf[4];
#pragma unroll
      for (int m = 0; m < 4; ++m) {
        const int arow = wr * 64 + m * 16 + c;
        const int slot = (kk * 4 + g) ^ (arow & 7);
        af[m] = *(const short8*)(Abuf + arow * 64 + slot * 8);
      }
#pragma unroll
      for (int nn = 0; nn < 4; ++nn) {
        const int brow = wc * 64 + nn * 16 + c;
        const int slot = (kk * 4 + g) ^ (brow & 7);
        bf[nn] = *(const short8*)(Bbuf + brow * 64 + slot * 8);
      }
#pragma unroll
      for (int m = 0; m < 4; ++m)
#pragma unroll
        for (int nn = 0; nn < 4; ++nn)
          acc[m][nn] = __builtin_amdgcn_mfma_f32_16x16x32_bf16(
              af[m], bf[nn], acc[m][nn], 0, 0, 0);
    }
  }
#pragma unroll
  for (int m = 0; m < 4; ++m)
#pragma unroll
    for (int nn = 0; nn < 4; ++nn)
#pragma unroll
      for (int rg = 0; rg < 4; ++rg) {
        const int row = m0 + wr * 64 + m * 16 + 4 * g + rg;
        const int col = nb * 128 + wc * 64 + nn * 16 + c;
        C[(size_t)row * DM + col] = f2bf(acc[m][nn][rg]);
      }
}

// ---------------------------------------------------------------------------
// out[4096][512] = Ah*Bh^T + Al*Bh^T + Ah*Bl^T   (split-bf16, f32 accum)
// ---------------------------------------------------------------------------
__global__ __launch_bounds__(256) void k_out_mfma(
    const unsigned short* __restrict__ Ah, const unsigned short* __restrict__ Al,
    const unsigned short* __restrict__ Bh, const unsigned short* __restrict__ Bl,
    float* __restrict__ C) {
  __shared__ unsigned short bufAh[64 * 64], bufAl[64 * 64];
  __shared__ unsigned short bufBh[64 * 64], bufBl[64 * 64];
  const int tid = threadIdx.x, w = tid >> 6, lane = tid & 63;
  const int c = lane & 15, g = lane >> 4;
  const int wr = w >> 1, wc = w & 1;
  const int bm = blockIdx.x, bn = blockIdx.y;
  const int lrow = lane >> 3, lslot = lane & 7;
  floatx4 acc[2][2];
#pragma unroll
  for (int mi = 0; mi < 2; ++mi)
#pragma unroll
    for (int ni = 0; ni < 2; ++ni) acc[mi][ni] = (floatx4){0.f, 0.f, 0.f, 0.f};

  for (int k0 = 0; k0 < DM; k0 += 64) {
    __syncthreads();
#pragma unroll
    for (int iq = 0; iq < 2; ++iq) {
      const int r0 = w * 16 + iq * 8;
      const int arow = r0 + lrow;
      const int sg = lslot ^ (arow & 7);
      GLOAD_LDS16(Ah + (size_t)(bm * 64 + arow) * DM + k0 + sg * 8, bufAh + r0 * 64);
      GLOAD_LDS16(Al + (size_t)(bm * 64 + arow) * DM + k0 + sg * 8, bufAl + r0 * 64);
      GLOAD_LDS16(Bh + (size_t)(bn * 64 + arow) * DM + k0 + sg * 8, bufBh + r0 * 64);
      GLOAD_LDS16(Bl + (size_t)(bn * 64 + arow) * DM + k0 + sg * 8, bufBl + r0 * 64);
    }
    __syncthreads();
#pragma unroll
    for (int kk = 0; kk < 2; ++kk) {
      short8 ah[2], al[2], bh[2], bl[2];
#pragma unroll
      for (int mi = 0; mi < 2; ++mi) {
        const int row = wr * 32 + mi * 16 + c;
        const int slot = (kk * 4 + g) ^ (row & 7);
        ah[mi] = *(const short8*)(bufAh + row * 64 + slot * 8);
        al[mi] = *(const short8*)(bufAl + row * 64 + slot * 8);
      }
#pragma unroll
      for (int ni = 0; ni < 2; ++ni) {
        const int row = wc * 32 + ni * 16 + c;
        const int slot = (kk * 4 + g) ^ (row & 7);
        bh[ni] = *(const short8*)(bufBh + row * 64 + slot * 8);
        bl[ni] = *(const short8*)(bufBl + row * 64 + slot * 8);
      }
#pragma unroll
      for (int mi = 0; mi < 2; ++mi)
#pragma unroll
        for (int ni = 0; ni < 2; ++ni) {
          acc[mi][ni] = __builtin_amdgcn_mfma_f32_16x16x32_bf16(
              ah[mi], bh[ni], acc[mi][ni], 0, 0, 0);
          acc[mi][ni] = __builtin_amdgcn_mfma_f32_16x16x32_bf16(
              al[mi], bh[ni], acc[mi][ni], 0, 0, 0);
          acc[mi][ni] = __builtin_amdgcn_mfma_f32_16x16x32_bf16(
              ah[mi], bl[ni], acc[mi][ni], 0, 0, 0);
        }
    }
  }
#pragma unroll
  for (int mi = 0; mi < 2; ++mi)
#pragma unroll
    for (int ni = 0; ni < 2; ++ni)
#pragma unroll
      for (int rg = 0; rg < 4; ++rg) {
        const int row = bm * 64 + wr * 32 + mi * 16 + 4 * g + rg;
        const int col = bn * 64 + wc * 32 + ni * 16 + c;
        C[(size_t)row * DM + col] = acc[mi][ni][rg];
      }
}

// ---------------------------------------------------------------------------
// Flash MFMA attention with cooperative double-buffered LDS staging.
// Block = 64 q rows (4 waves x 16), grid (16,8,4). Per 64-key tile t, the
// block stages K(64x64), V^T(64x64), R-window(128x64) via coalesced
// global_load_lds (XOR slot swizzle, rule-21 both-sides); waves read MFMA
// fragments from LDS at the 32-bank floor. One barrier per tile; tile t+1
// staged before compute of t (latency hidden under compute).
// score(i,j) = qk_i.k_j + qr_i.r[j-i+1023], valid j <= i+1024.
// ---------------------------------------------------------------------------
__global__ __launch_bounds__(256, 2) void k_attn_mfma(
    const unsigned short* __restrict__ q, const unsigned short* __restrict__ k,
    const unsigned short* __restrict__ vt, const unsigned short* __restrict__ r,
    const float* __restrict__ bk, const float* __restrict__ br,
    unsigned short* __restrict__ aoh, unsigned short* __restrict__ aol) {
  __shared__ unsigned short Kt[2][64 * 64];     // 16 KB
  __shared__ unsigned short VTt[2][64 * 64];    // 16 KB
  __shared__ unsigned short Rt[2][128 * 64];    // 32 KB
  __shared__ unsigned short P[4][16][76];       // 9.5 KB

  const int tid = threadIdx.x;
  const int w = tid >> 6;          // wave = qsub
  const int lane = tid & 63;
  const int c = lane & 15;
  const int g = lane >> 4;
  const int n = blockIdx.y;
  const int b = blockIdx.z;
  const int grp = (n + NHEAD * b) >> 4;   // co-resident pair balance
  const int i0 = (grp ? (15 - (int)blockIdx.x) : (int)blockIdx.x) * 64;
  const int qb = i0 + w * 16;
  const unsigned short* vtbn = vt + (size_t)(b * NHEAD + n) * DHEAD * KLEN;
  const unsigned short* kbase = k + (size_t)(b * KLEN) * DM + n * DHEAD;
  const unsigned short* rbase_p = r + n * DHEAD;

  const int srow = tid >> 3;       // 0..31 staging row-in-pass
  const int sslot = tid & 7;       // LDS 16B slot

  // Q fragments, biases folded, pre-scaled by 1/8
  short8 aqk[2], aqr[2];
  {
    const unsigned short* qrow =
        q + ((size_t)(b * QLEN) + qb + c) * DM + n * DHEAD;
#pragma unroll
    for (int kb2 = 0; kb2 < 2; ++kb2) {
      short8 qv = *(const short8*)(qrow + kb2 * 32 + g * 8);
#pragma unroll
      for (int j = 0; j < 8; ++j) {
        int d = kb2 * 32 + g * 8 + j;
        float f = bf2f((unsigned short)qv[j]);
        aqk[kb2][j] = (short)f2bf((f + bk[n * DHEAD + d]) * 0.125f);
        aqr[kb2][j] = (short)f2bf((f + br[n * DHEAD + d]) * 0.125f);
      }
    }
  }

  floatx4 o[4];
#pragma unroll
  for (int t = 0; t < 4; ++t) o[t] = (floatx4){0.f, 0.f, 0.f, 0.f};
  float m[4], lsum[4];
#pragma unroll
  for (int rg = 0; rg < 4; ++rg) { m[rg] = -1e30f; lsum[rg] = 0.f; }

  const int nkb = i0 / 64 + 17;

  // cooperative stage of tile t into buffer buf (8 coalesced 16B loads/thread)
  auto STAGE = [&](int t, int buf) {
    const int j0 = t * 64;
    const int rwin = j0 - i0 + 960;   // R window base row (multiple of 64)
#pragma unroll
    for (int p = 0; p < 2; ++p) {
      const int row = p * 32 + srow;
      const int sg = sslot ^ (row & 7);
      GLOAD_LDS16(kbase + (size_t)(j0 + row) * DM + sg * 8,
                  &Kt[buf][row * 64 + sslot * 8]);
    }
#pragma unroll
    for (int p = 0; p < 2; ++p) {
      const int row = p * 32 + srow;   // d
      const int sg = sslot ^ (row & 7);
      GLOAD_LDS16(vtbn + (size_t)row * KLEN + j0 + sg * 8,
                  &VTt[buf][row * 64 + sslot * 8]);
    }
#pragma unroll
    for (int p = 0; p < 4; ++p) {
      const int row = p * 32 + srow;   // 0..127
      const int grow = min(rwin + row, KLEN - 1);
      const int sg = sslot ^ (row & 7);
      GLOAD_LDS16(rbase_p + (size_t)grow * DM + sg * 8,
                  &Rt[buf][row * 64 + sslot * 8]);
    }
  };

  STAGE(0, 0);
  __syncthreads();
  int cur = 0;

  const int s0 = (g ^ (c & 7)) * 8;          // k-slot 0 byte offset (elements)
  const int s1 = ((4 + g) ^ (c & 7)) * 8;    // k-slot 1

  for (int t = 0; t < nkb; ++t) {
    if (t + 1 < nkb) STAGE(t + 1, cur ^ 1);
    const unsigned short* Kc = &Kt[cur][0];
    const unsigned short* Vc = &VTt[cur][0];
    const unsigned short* Rc = &Rt[cur][0];

    // BD tiles from staged R + register-shuffle diagonal gather
    float sh[5][4];
#pragma unroll
    for (int tau5 = 0; tau5 < 5; ++tau5) {
      const int lr = (tau5 + 3 - w) * 16 + c;   // local R row
      short8 rf0 = *(const short8*)(Rc + lr * 64 + s0);
      short8 rf1 = *(const short8*)(Rc + lr * 64 + s1);
      floatx4 bd = (floatx4){0.f, 0.f, 0.f, 0.f};
      bd = __builtin_amdgcn_mfma_f32_16x16x32_bf16(aqr[0], rf0, bd, 0, 0, 0);
      bd = __builtin_amdgcn_mfma_f32_16x16x32_bf16(aqr[1], rf1, bd, 0, 0, 0);
#pragma unroll
      for (int rg = 0; rg < 4; ++rg) {
        const int srcl = (g << 4) | ((15 + c - 4 * g - rg) & 15);
        sh[tau5][rg] = __shfl(bd[rg], srcl, 64);
      }
    }

    // AC + gather + mask
    floatx4 s[4];
    const bool lastblk = (t == nkb - 1);
#pragma unroll
    for (int tau = 0; tau < 4; ++tau) {
      const int kr = tau * 16 + c;
      short8 kf0 = *(const short8*)(Kc + kr * 64 + s0);
      short8 kf1 = *(const short8*)(Kc + kr * 64 + s1);
      floatx4 acc = (floatx4){0.f, 0.f, 0.f, 0.f};
      acc = __builtin_amdgcn_mfma_f32_16x16x32_bf16(aqk[0], kf0, acc, 0, 0, 0);
      acc = __builtin_amdgcn_mfma_f32_16x16x32_bf16(aqk[1], kf1, acc, 0, 0, 0);
#pragma unroll
      for (int rg = 0; rg < 4; ++rg) {
        const int ql = 4 * g + rg;
        float sv = acc[rg] + ((c > ql) ? sh[tau + 1][rg] : sh[tau][rg]);
        if (lastblk && (tau * 16 + c > w * 16 + ql)) sv = -1e30f;
        s[tau][rg] = sv;
      }
    }

    // online softmax
    float fac[4];
#pragma unroll
    for (int rg = 0; rg < 4; ++rg) {
      float mx = fmaxf(fmaxf(s[0][rg], s[1][rg]), fmaxf(s[2][rg], s[3][rg]));
#pragma unroll
      for (int shm = 1; shm < 16; shm <<= 1) mx = fmaxf(mx, __shfl_xor(mx, shm, 64));
      float mn = fmaxf(m[rg], mx);
      fac[rg] = __expf(m[rg] - mn);
      m[rg] = mn;
    }
    float rsum[4] = {0.f, 0.f, 0.f, 0.f};
#pragma unroll
    for (int tau = 0; tau < 4; ++tau) {
#pragma unroll
      for (int rg = 0; rg < 4; ++rg) {
        float p = __expf(s[tau][rg] - m[rg]);
        rsum[rg] += p;
        P[w][4 * g + rg][tau * 16 + c] = f2bf(p);
      }
    }
#pragma unroll
    for (int rg = 0; rg < 4; ++rg) {
      float rs = rsum[rg];
#pragma unroll
      for (int shm = 1; shm < 16; shm <<= 1) rs += __shfl_xor(rs, shm, 64);
      lsum[rg] = lsum[rg] * fac[rg] + rs;
#pragma unroll
      for (int td = 0; td < 4; ++td) o[td][rg] *= fac[rg];
    }

    // PV: P from wave-private LDS, V^T from staged LDS
    short8 pa0 = *(const short8*)&P[w][c][g * 8];
    short8 pa1 = *(const short8*)&P[w][c][32 + g * 8];
#pragma unroll
    for (int td = 0; td < 4; ++td) {
      const int vrow = td * 16 + c;
      short8 vb0 = *(const short8*)(Vc + vrow * 64 + s0);
      short8 vb1 = *(const short8*)(Vc + vrow * 64 + s1);
      o[td] = __builtin_amdgcn_mfma_f32_16x16x32_bf16(pa0, vb0, o[td], 0, 0, 0);
      o[td] = __builtin_amdgcn_mfma_f32_16x16x32_bf16(pa1, vb1, o[td], 0, 0, 0);
    }
    __syncthreads();
    cur ^= 1;
  }

  // epilogue: each wave owns its 16 q rows
#pragma unroll
  for (int rg = 0; rg < 4; ++rg) {
    const int ql = 4 * g + rg;
    const float invl = 1.0f / lsum[rg];
#pragma unroll
    for (int td = 0; td < 4; ++td) {
      float val = o[td][rg] * invl;
      unsigned short hi = f2bf(val);
      float lo = val - bf2f(hi);
      size_t off = ((size_t)(b * QLEN) + qb + ql) * DM + n * DHEAD + td * 16 + c;
      aoh[off] = hi;
      aol[off] = f2bf(lo);
    }
  }
}

// ---------------------------------------------------------------------------
extern "C" void kernel_launch(void* const* d_in, const int* in_sizes, int n_in,
                              void* d_out, int out_size, void* d_ws, size_t ws_size,
                              hipStream_t stream) {
  const float* x  = (const float*)d_in[0];
  const float* p  = (const float*)d_in[1];
  const float* Wq = (const float*)d_in[2];
  const float* Wk = (const float*)d_in[3];
  const float* Wv = (const float*)d_in[4];
  const float* Wo = (const float*)d_in[5];
  const float* Wp = (const float*)d_in[6];
  const float* bk = (const float*)d_in[7];
  const float* br = (const float*)d_in[8];
  float* out = (float*)d_out;

  unsigned short* q_  = (unsigned short*)d_ws;        // 2M u16
  unsigned short* k_  = q_  + (size_t)2097152;        // 4M
  unsigned short* v_  = k_  + (size_t)4194304;        // 4M
  unsigned short* r_  = v_  + (size_t)4194304;        // 1M
  unsigned short* xb  = r_  + (size_t)1048576;        // 4M
  unsigned short* pb  = xb  + (size_t)4194304;        // 1M
  unsigned short* wt  = pb  + (size_t)1048576;        // 1M
  unsigned short* woh = wt  + (size_t)1048576;        // 256K
  unsigned short* wol = woh + (size_t)262144;         // 256K
  unsigned short* aoh = wol + (size_t)262144;         // 2M
  unsigned short* aol = aoh + (size_t)2097152;        // 2M
  unsigned short* vt_ = aol + (size_t)2097152;        // 4M

  k_f32bf16<<<2048, 256, 0, stream>>>(x, xb, (B_SZ * KLEN * DM) / 8);
  k_f32bf16<<<512, 256, 0, stream>>>(p, pb, (KLEN * DM) / 8);
  k_wtrans<<<dim3(8, 8, 4), 256, 0, stream>>>(Wq, Wk, Wv, Wp, wt);
  k_wosplit<<<128, 256, 0, stream>>>(Wo, woh, wol, (DM * DM) / 8);
  k_proj_mfma<<<dim3(176, 4), 256, 0, stream>>>(xb, pb, wt, q_, k_, v_, r_);
  k_vtrans<<<dim3(KLEN / 64, NHEAD * B_SZ), 256, 0, stream>>>(v_, vt_);
  k_attn_mfma<<<dim3(16, 8, 4), 256, 0, stream>>>(
      q_, k_, vt_, r_, bk, br, aoh, aol);
  k_out_mfma<<<dim3(64, 8), 256, 0, stream>>>(aoh, aol, woh, wol, out);
}

// Round 7
// 129.342 us; speedup vs baseline: 1.6063x; 1.0672x over previous
//
#include <hip/hip_runtime.h>
#include <hip/hip_bf16.h>
#include <stddef.h>
#include <stdint.h>

#define DM    512
#define NHEAD 8
#define DHEAD 64
#define QLEN  1024
#define KLEN  2048
#define MLEN  1024
#define B_SZ  4

typedef __attribute__((ext_vector_type(8))) short short8;
typedef __attribute__((ext_vector_type(8))) unsigned short ushort8;
typedef __attribute__((ext_vector_type(4))) float floatx4;

static __device__ __forceinline__ unsigned short f2bf(float f) {
  unsigned int u = __float_as_uint(f);
  unsigned int r = (u + 0x7FFFu + ((u >> 16) & 1u)) >> 16;
  return (unsigned short)r;
}
static __device__ __forceinline__ float bf2f(unsigned short h) {
  return __uint_as_float(((unsigned int)h) << 16);
}

#define GLOAD_LDS16(gsrc, ldst)                                               \
  __builtin_amdgcn_global_load_lds(                                           \
      (const __attribute__((address_space(1))) unsigned int*)(gsrc),          \
      (__attribute__((address_space(3))) unsigned int*)(ldst), 16, 0, 0)

// ---------------------------------------------------------------------------
// f32 -> bf16 elementwise (8 per thread)
// ---------------------------------------------------------------------------
__global__ __launch_bounds__(256) void k_f32bf16(
    const float* __restrict__ in, unsigned short* __restrict__ out, int n8) {
  int i = blockIdx.x * 256 + threadIdx.x;
  if (i < n8) {
    float4 a = *(const float4*)(in + (size_t)i * 8);
    float4 b = *(const float4*)(in + (size_t)i * 8 + 4);
    ushort8 o;
    o[0] = f2bf(a.x); o[1] = f2bf(a.y); o[2] = f2bf(a.z); o[3] = f2bf(a.w);
    o[4] = f2bf(b.x); o[5] = f2bf(b.y); o[6] = f2bf(b.z); o[7] = f2bf(b.w);
    *(ushort8*)(out + (size_t)i * 8) = o;
  }
}

// ---------------------------------------------------------------------------
// f32 -> (hi, lo) bf16 split
// ---------------------------------------------------------------------------
__global__ __launch_bounds__(256) void k_wosplit(
    const float* __restrict__ in, unsigned short* __restrict__ oh,
    unsigned short* __restrict__ ol, int n8) {
  int i = blockIdx.x * 256 + threadIdx.x;
  if (i < n8) {
    ushort8 vh, vl;
#pragma unroll
    for (int j = 0; j < 8; ++j) {
      float f = in[(size_t)i * 8 + j];
      unsigned short h = f2bf(f);
      vh[j] = h;
      vl[j] = f2bf(f - bf2f(h));
    }
    *(ushort8*)(oh + (size_t)i * 8) = vh;
    *(ushort8*)(ol + (size_t)i * 8) = vl;
  }
}

// ---------------------------------------------------------------------------
// Transpose-convert the 4 projection weights: W[512 k][512 n] f32 ->
// Wt[512 n][512 k] bf16 (4 matrices stacked, stride 262144).
// ---------------------------------------------------------------------------
__global__ __launch_bounds__(256) void k_wtrans(
    const float* __restrict__ W0, const float* __restrict__ W1,
    const float* __restrict__ W2, const float* __restrict__ W3,
    unsigned short* __restrict__ wt) {
  __shared__ float tile[64][65];
  const int z = blockIdx.z;
  const float* W = (z == 0) ? W0 : (z == 1) ? W1 : (z == 2) ? W2 : W3;
  unsigned short* out = wt + (size_t)z * 262144;
  const int tid = threadIdx.x;
  const int row = tid >> 2, c0 = (tid & 3) * 16;
  const int kb = blockIdx.y * 64, nb = blockIdx.x * 64;
#pragma unroll
  for (int j = 0; j < 4; ++j) {
    float4 ld = *(const float4*)(W + (size_t)(kb + row) * DM + nb + c0 + j * 4);
    tile[row][c0 + j * 4 + 0] = ld.x;
    tile[row][c0 + j * 4 + 1] = ld.y;
    tile[row][c0 + j * 4 + 2] = ld.z;
    tile[row][c0 + j * 4 + 3] = ld.w;
  }
  __syncthreads();
  unsigned short ob[16];
#pragma unroll
  for (int j = 0; j < 16; ++j) ob[j] = f2bf(tile[c0 + j][row]);
  unsigned short* orow = out + (size_t)(nb + row) * DM + kb + c0;
  *(ushort8*)(orow) = *(ushort8*)&ob[0];
  *(ushort8*)(orow + 8) = *(ushort8*)&ob[8];
}

// ---------------------------------------------------------------------------
// v_ [B*KLEN][512] bf16 -> vt [b][n][d][KLEN] bf16 (global V transpose)
// ---------------------------------------------------------------------------
__global__ __launch_bounds__(256) void k_vtrans(
    const unsigned short* __restrict__ v_, unsigned short* __restrict__ vt) {
  __shared__ unsigned short tile[64][72];
  const int tid = threadIdx.x;
  const int row = tid >> 2, c0 = (tid & 3) * 16;
  const int kt = blockIdx.x;            // key tile (64 keys)
  const int bn = blockIdx.y;            // b*8+n
  const int bb = bn >> 3, n = bn & 7;
  const unsigned short* src =
      v_ + ((size_t)(bb * KLEN) + kt * 64 + row) * DM + n * DHEAD + c0;
  *(ushort8*)&tile[row][c0] = *(const ushort8*)src;
  *(ushort8*)&tile[row][c0 + 8] = *(const ushort8*)(src + 8);
  __syncthreads();
  unsigned short ob[16];
#pragma unroll
  for (int j = 0; j < 16; ++j) ob[j] = tile[c0 + j][row];
  unsigned short* dst =
      vt + ((size_t)bn * DHEAD + row) * KLEN + kt * 64 + c0;
  *(ushort8*)dst = *(ushort8*)&ob[0];
  *(ushort8*)(dst + 8) = *(ushort8*)&ob[8];
}

// ---------------------------------------------------------------------------
// Fused bf16 MFMA projection GEMM: C[M][512] = A[M][512] * Wt[512][512]^T
// ---------------------------------------------------------------------------
__global__ __launch_bounds__(256) void k_proj_mfma(
    const unsigned short* __restrict__ xb, const unsigned short* __restrict__ pb,
    const unsigned short* __restrict__ wt,
    unsigned short* __restrict__ q_, unsigned short* __restrict__ k_,
    unsigned short* __restrict__ v_, unsigned short* __restrict__ r_) {
  __shared__ unsigned short Abuf[128 * 64];
  __shared__ unsigned short Bbuf[128 * 64];
  const int tid = threadIdx.x, w = tid >> 6, lane = tid & 63;
  const int c = lane & 15, g = lane >> 4;
  const int wr = w >> 1, wc = w & 1;
  const int mb = blockIdx.x, nb = blockIdx.y;
  int prob, mloc;
  const unsigned short* A;
  unsigned short* C;
  if (mb < 32)        { prob = 0; mloc = mb;       A = xb; C = q_; }
  else if (mb < 96)   { prob = 1; mloc = mb - 32;  A = xb; C = k_; }
  else if (mb < 160)  { prob = 2; mloc = mb - 96;  A = xb; C = v_; }
  else                { prob = 3; mloc = mb - 160; A = pb; C = r_; }
  const unsigned short* W = wt + (size_t)prob * 262144;
  const int m0 = mloc * 128;
  const int lrow = lane >> 3, lslot = lane & 7;

  floatx4 acc[4][4];
#pragma unroll
  for (int m = 0; m < 4; ++m)
#pragma unroll
    for (int nn = 0; nn < 4; ++nn) acc[m][nn] = (floatx4){0.f, 0.f, 0.f, 0.f};

  for (int k0 = 0; k0 < DM; k0 += 64) {
    __syncthreads();
#pragma unroll
    for (int iq = 0; iq < 4; ++iq) {
      const int r0 = w * 32 + iq * 8;
      const int arow = r0 + lrow;
      const int mrow = m0 + arow;
      const int grow =
          (prob == 0) ? ((mrow >> 10) * KLEN + (mrow & 1023) + MLEN) : mrow;
      const int sgA = lslot ^ (arow & 7);
      GLOAD_LDS16(A + (size_t)grow * DM + k0 + sgA * 8, Abuf + r0 * 64);
      const int nrow = nb * 128 + arow;
      GLOAD_LDS16(W + (size_t)nrow * DM + k0 + sgA * 8, Bbuf + r0 * 64);
    }
    __syncthreads();
#pragma unroll
    for (int kk = 0; kk < 2; ++kk) {
      short8 af[4], bf[4];
#pragma unroll
      for (int m = 0; m < 4; ++m) {
        const int arow = wr * 64 + m * 16 + c;
        const int slot = (kk * 4 + g) ^ (arow & 7);
        af[m] = *(const short8*)(Abuf + arow * 64 + slot * 8);
      }
#pragma unroll
      for (int nn = 0; nn < 4; ++nn) {
        const int brow = wc * 64 + nn * 16 + c;
        const int slot = (kk * 4 + g) ^ (brow & 7);
        bf[nn] = *(const short8*)(Bbuf + brow * 64 + slot * 8);
      }
#pragma unroll
      for (int m = 0; m < 4; ++m)
#pragma unroll
        for (int nn = 0; nn < 4; ++nn)
          acc[m][nn] = __builtin_amdgcn_mfma_f32_16x16x32_bf16(
              af[m], bf[nn], acc[m][nn], 0, 0, 0);
    }
  }
#pragma unroll
  for (int m = 0; m < 4; ++m)
#pragma unroll
    for (int nn = 0; nn < 4; ++nn)
#pragma unroll
      for (int rg = 0; rg < 4; ++rg) {
        const int row = m0 + wr * 64 + m * 16 + 4 * g + rg;
        const int col = nb * 128 + wc * 64 + nn * 16 + c;
        C[(size_t)row * DM + col] = f2bf(acc[m][nn][rg]);
      }
}

// ---------------------------------------------------------------------------
// out[4096][512] = Ah*Bh^T + Al*Bh^T + Ah*Bl^T   (split-bf16, f32 accum)
// ---------------------------------------------------------------------------
__global__ __launch_bounds__(256) void k_out_mfma(
    const unsigned short* __restrict__ Ah, const unsigned short* __restrict__ Al,
    const unsigned short* __restrict__ Bh, const unsigned short* __restrict__ Bl,
    float* __restrict__ C) {
  __shared__ unsigned short bufAh[64 * 64], bufAl[64 * 64];
  __shared__ unsigned short bufBh[64 * 64], bufBl[64 * 64];
  const int tid = threadIdx.x, w = tid >> 6, lane = tid & 63;
  const int c = lane & 15, g = lane >> 4;
  const int wr = w >> 1, wc = w & 1;
  const int bm = blockIdx.x, bn = blockIdx.y;
  const int lrow = lane >> 3, lslot = lane & 7;
  floatx4 acc[2][2];
#pragma unroll
  for (int mi = 0; mi < 2; ++mi)
#pragma unroll
    for (int ni = 0; ni < 2; ++ni) acc[mi][ni] = (floatx4){0.f, 0.f, 0.f, 0.f};

  for (int k0 = 0; k0 < DM; k0 += 64) {
    __syncthreads();
#pragma unroll
    for (int iq = 0; iq < 2; ++iq) {
      const int r0 = w * 16 + iq * 8;
      const int arow = r0 + lrow;
      const int sg = lslot ^ (arow & 7);
      GLOAD_LDS16(Ah + (size_t)(bm * 64 + arow) * DM + k0 + sg * 8, bufAh + r0 * 64);
      GLOAD_LDS16(Al + (size_t)(bm * 64 + arow) * DM + k0 + sg * 8, bufAl + r0 * 64);
      GLOAD_LDS16(Bh + (size_t)(bn * 64 + arow) * DM + k0 + sg * 8, bufBh + r0 * 64);
      GLOAD_LDS16(Bl + (size_t)(bn * 64 + arow) * DM + k0 + sg * 8, bufBl + r0 * 64);
    }
    __syncthreads();
#pragma unroll
    for (int kk = 0; kk < 2; ++kk) {
      short8 ah[2], al[2], bh[2], bl[2];
#pragma unroll
      for (int mi = 0; mi < 2; ++mi) {
        const int row = wr * 32 + mi * 16 + c;
        const int slot = (kk * 4 + g) ^ (row & 7);
        ah[mi] = *(const short8*)(bufAh + row * 64 + slot * 8);
        al[mi] = *(const short8*)(bufAl + row * 64 + slot * 8);
      }
#pragma unroll
      for (int ni = 0; ni < 2; ++ni) {
        const int row = wc * 32 + ni * 16 + c;
        const int slot = (kk * 4 + g) ^ (row & 7);
        bh[ni] = *(const short8*)(bufBh + row * 64 + slot * 8);
        bl[ni] = *(const short8*)(bufBl + row * 64 + slot * 8);
      }
#pragma unroll
      for (int mi = 0; mi < 2; ++mi)
#pragma unroll
        for (int ni = 0; ni < 2; ++ni) {
          acc[mi][ni] = __builtin_amdgcn_mfma_f32_16x16x32_bf16(
              ah[mi], bh[ni], acc[mi][ni], 0, 0, 0);
          acc[mi][ni] = __builtin_amdgcn_mfma_f32_16x16x32_bf16(
              al[mi], bh[ni], acc[mi][ni], 0, 0, 0);
          acc[mi][ni] = __builtin_amdgcn_mfma_f32_16x16x32_bf16(
              ah[mi], bl[ni], acc[mi][ni], 0, 0, 0);
        }
    }
  }
#pragma unroll
  for (int mi = 0; mi < 2; ++mi)
#pragma unroll
    for (int ni = 0; ni < 2; ++ni)
#pragma unroll
      for (int rg = 0; rg < 4; ++rg) {
        const int row = bm * 64 + wr * 32 + mi * 16 + 4 * g + rg;
        const int col = bn * 64 + wc * 32 + ni * 16 + c;
        C[(size_t)row * DM + col] = acc[mi][ni][rg];
      }
}

// ---------------------------------------------------------------------------
// Flash MFMA attention, staged LDS + LDS-pipe-reduced softmax:
//   - per-lane partial lsum (cross-lane reduce deferred to epilogue)
//   - sh[4] carried to next tile's sh[0] (BD window overlap)
//   - defer-max (THR=8): skip o/lsum rescale when max doesn't grow
//   - s_setprio(1) around MFMA clusters
// ---------------------------------------------------------------------------
__global__ __launch_bounds__(256, 2) void k_attn_mfma(
    const unsigned short* __restrict__ q, const unsigned short* __restrict__ k,
    const unsigned short* __restrict__ vt, const unsigned short* __restrict__ r,
    const float* __restrict__ bk, const float* __restrict__ br,
    unsigned short* __restrict__ aoh, unsigned short* __restrict__ aol) {
  __shared__ unsigned short Kt[2][64 * 64];     // 16 KB
  __shared__ unsigned short VTt[2][64 * 64];    // 16 KB
  __shared__ unsigned short Rt[2][128 * 64];    // 32 KB
  __shared__ unsigned short P[4][16][76];       // 9.5 KB

  const int tid = threadIdx.x;
  const int w = tid >> 6;          // wave = qsub
  const int lane = tid & 63;
  const int c = lane & 15;
  const int g = lane >> 4;
  const int n = blockIdx.y;
  const int b = blockIdx.z;
  const int grp = (n + NHEAD * b) >> 4;   // co-resident pair balance
  const int i0 = (grp ? (15 - (int)blockIdx.x) : (int)blockIdx.x) * 64;
  const int qb = i0 + w * 16;
  const unsigned short* vtbn = vt + (size_t)(b * NHEAD + n) * DHEAD * KLEN;
  const unsigned short* kbase = k + (size_t)(b * KLEN) * DM + n * DHEAD;
  const unsigned short* rbase_p = r + n * DHEAD;

  const int srow = tid >> 3;
  const int sslot = tid & 7;

  // Q fragments, biases folded, pre-scaled by 1/8
  short8 aqk[2], aqr[2];
  {
    const unsigned short* qrow =
        q + ((size_t)(b * QLEN) + qb + c) * DM + n * DHEAD;
#pragma unroll
    for (int kb2 = 0; kb2 < 2; ++kb2) {
      short8 qv = *(const short8*)(qrow + kb2 * 32 + g * 8);
#pragma unroll
      for (int j = 0; j < 8; ++j) {
        int d = kb2 * 32 + g * 8 + j;
        float f = bf2f((unsigned short)qv[j]);
        aqk[kb2][j] = (short)f2bf((f + bk[n * DHEAD + d]) * 0.125f);
        aqr[kb2][j] = (short)f2bf((f + br[n * DHEAD + d]) * 0.125f);
      }
    }
  }

  floatx4 o[4];
#pragma unroll
  for (int t = 0; t < 4; ++t) o[t] = (floatx4){0.f, 0.f, 0.f, 0.f};
  float m[4], lsum[4], shc[4];
#pragma unroll
  for (int rg = 0; rg < 4; ++rg) { m[rg] = -1e30f; lsum[rg] = 0.f; shc[rg] = 0.f; }

  const int nkb = i0 / 64 + 17;

  auto STAGE = [&](int t, int buf) {
    const int j0 = t * 64;
    const int rwin = j0 - i0 + 960;
#pragma unroll
    for (int p = 0; p < 2; ++p) {
      const int row = p * 32 + srow;
      const int sg = sslot ^ (row & 7);
      GLOAD_LDS16(kbase + (size_t)(j0 + row) * DM + sg * 8,
                  &Kt[buf][row * 64 + sslot * 8]);
    }
#pragma unroll
    for (int p = 0; p < 2; ++p) {
      const int row = p * 32 + srow;
      const int sg = sslot ^ (row & 7);
      GLOAD_LDS16(vtbn + (size_t)row * KLEN + j0 + sg * 8,
                  &VTt[buf][row * 64 + sslot * 8]);
    }
#pragma unroll
    for (int p = 0; p < 4; ++p) {
      const int row = p * 32 + srow;
      const int grow = min(rwin + row, KLEN - 1);
      const int sg = sslot ^ (row & 7);
      GLOAD_LDS16(rbase_p + (size_t)grow * DM + sg * 8,
                  &Rt[buf][row * 64 + sslot * 8]);
    }
  };

  STAGE(0, 0);
  __syncthreads();
  int cur = 0;

  const int s0 = (g ^ (c & 7)) * 8;
  const int s1 = ((4 + g) ^ (c & 7)) * 8;

  for (int t = 0; t < nkb; ++t) {
    if (t + 1 < nkb) STAGE(t + 1, cur ^ 1);
    const unsigned short* Kc = &Kt[cur][0];
    const unsigned short* Vc = &VTt[cur][0];
    const unsigned short* Rc = &Rt[cur][0];

    // BD tiles: sh[0] carried from previous tile's sh[4] (window overlap)
    float sh[5][4];
    if (t == 0) {
      const int lr = (3 - w) * 16 + c;
      short8 rf0 = *(const short8*)(Rc + lr * 64 + s0);
      short8 rf1 = *(const short8*)(Rc + lr * 64 + s1);
      floatx4 bd = (floatx4){0.f, 0.f, 0.f, 0.f};
      bd = __builtin_amdgcn_mfma_f32_16x16x32_bf16(aqr[0], rf0, bd, 0, 0, 0);
      bd = __builtin_amdgcn_mfma_f32_16x16x32_bf16(aqr[1], rf1, bd, 0, 0, 0);
#pragma unroll
      for (int rg = 0; rg < 4; ++rg) {
        const int srcl = (g << 4) | ((15 + c - 4 * g - rg) & 15);
        sh[0][rg] = __shfl(bd[rg], srcl, 64);
      }
    } else {
#pragma unroll
      for (int rg = 0; rg < 4; ++rg) sh[0][rg] = shc[rg];
    }
#pragma unroll
    for (int tau5 = 1; tau5 < 5; ++tau5) {
      const int lr = (tau5 + 3 - w) * 16 + c;
      short8 rf0 = *(const short8*)(Rc + lr * 64 + s0);
      short8 rf1 = *(const short8*)(Rc + lr * 64 + s1);
      floatx4 bd = (floatx4){0.f, 0.f, 0.f, 0.f};
      bd = __builtin_amdgcn_mfma_f32_16x16x32_bf16(aqr[0], rf0, bd, 0, 0, 0);
      bd = __builtin_amdgcn_mfma_f32_16x16x32_bf16(aqr[1], rf1, bd, 0, 0, 0);
#pragma unroll
      for (int rg = 0; rg < 4; ++rg) {
        const int srcl = (g << 4) | ((15 + c - 4 * g - rg) & 15);
        sh[tau5][rg] = __shfl(bd[rg], srcl, 64);
      }
    }
#pragma unroll
    for (int rg = 0; rg < 4; ++rg) shc[rg] = sh[4][rg];

    // AC + gather + mask
    floatx4 s[4];
    const bool lastblk = (t == nkb - 1);
    __builtin_amdgcn_s_setprio(1);
#pragma unroll
    for (int tau = 0; tau < 4; ++tau) {
      const int kr = tau * 16 + c;
      short8 kf0 = *(const short8*)(Kc + kr * 64 + s0);
      short8 kf1 = *(const short8*)(Kc + kr * 64 + s1);
      floatx4 acc = (floatx4){0.f, 0.f, 0.f, 0.f};
      acc = __builtin_amdgcn_mfma_f32_16x16x32_bf16(aqk[0], kf0, acc, 0, 0, 0);
      acc = __builtin_amdgcn_mfma_f32_16x16x32_bf16(aqk[1], kf1, acc, 0, 0, 0);
#pragma unroll
      for (int rg = 0; rg < 4; ++rg) {
        const int ql = 4 * g + rg;
        float sv = acc[rg] + ((c > ql) ? sh[tau + 1][rg] : sh[tau][rg]);
        if (lastblk && (tau * 16 + c > w * 16 + ql)) sv = -1e30f;
        s[tau][rg] = sv;
      }
    }
    __builtin_amdgcn_s_setprio(0);

    // online softmax: row max (cross-lane), defer-max rescale, per-lane sums
    float mx[4];
    bool ok = true;
#pragma unroll
    for (int rg = 0; rg < 4; ++rg) {
      float v2 = fmaxf(fmaxf(s[0][rg], s[1][rg]), fmaxf(s[2][rg], s[3][rg]));
#pragma unroll
      for (int shm = 1; shm < 16; shm <<= 1) v2 = fmaxf(v2, __shfl_xor(v2, shm, 64));
      mx[rg] = v2;
      ok = ok && (v2 <= m[rg] + 8.0f);
    }
    if (!__all(ok)) {
#pragma unroll
      for (int rg = 0; rg < 4; ++rg) {
        float mn = fmaxf(m[rg], mx[rg]);
        float fac = __expf(m[rg] - mn);
        m[rg] = mn;
        lsum[rg] *= fac;
#pragma unroll
        for (int td = 0; td < 4; ++td) o[td][rg] *= fac;
      }
    }
#pragma unroll
    for (int tau = 0; tau < 4; ++tau) {
#pragma unroll
      for (int rg = 0; rg < 4; ++rg) {
        float p = __expf(s[tau][rg] - m[rg]);
        lsum[rg] += p;
        P[w][4 * g + rg][tau * 16 + c] = f2bf(p);
      }
    }

    // PV
    short8 pa0 = *(const short8*)&P[w][c][g * 8];
    short8 pa1 = *(const short8*)&P[w][c][32 + g * 8];
    __builtin_amdgcn_s_setprio(1);
#pragma unroll
    for (int td = 0; td < 4; ++td) {
      const int vrow = td * 16 + c;
      short8 vb0 = *(const short8*)(Vc + vrow * 64 + s0);
      short8 vb1 = *(const short8*)(Vc + vrow * 64 + s1);
      o[td] = __builtin_amdgcn_mfma_f32_16x16x32_bf16(pa0, vb0, o[td], 0, 0, 0);
      o[td] = __builtin_amdgcn_mfma_f32_16x16x32_bf16(pa1, vb1, o[td], 0, 0, 0);
    }
    __builtin_amdgcn_s_setprio(0);
    __syncthreads();
    cur ^= 1;
  }

  // epilogue: reduce per-lane lsum partials across the 16-lane c-group
#pragma unroll
  for (int rg = 0; rg < 4; ++rg) {
    float L = lsum[rg];
#pragma unroll
    for (int shm = 1; shm < 16; shm <<= 1) L += __shfl_xor(L, shm, 64);
    lsum[rg] = L;
  }
#pragma unroll
  for (int rg = 0; rg < 4; ++rg) {
    const int ql = 4 * g + rg;
    const float invl = 1.0f / lsum[rg];
#pragma unroll
    for (int td = 0; td < 4; ++td) {
      float val = o[td][rg] * invl;
      unsigned short hi = f2bf(val);
      float lo = val - bf2f(hi);
      size_t off = ((size_t)(b * QLEN) + qb + ql) * DM + n * DHEAD + td * 16 + c;
      aoh[off] = hi;
      aol[off] = f2bf(lo);
    }
  }
}

// ---------------------------------------------------------------------------
extern "C" void kernel_launch(void* const* d_in, const int* in_sizes, int n_in,
                              void* d_out, int out_size, void* d_ws, size_t ws_size,
                              hipStream_t stream) {
  const float* x  = (const float*)d_in[0];
  const float* p  = (const float*)d_in[1];
  const float* Wq = (const float*)d_in[2];
  const float* Wk = (const float*)d_in[3];
  const float* Wv = (const float*)d_in[4];
  const float* Wo = (const float*)d_in[5];
  const float* Wp = (const float*)d_in[6];
  const float* bk = (const float*)d_in[7];
  const float* br = (const float*)d_in[8];
  float* out = (float*)d_out;

  unsigned short* q_  = (unsigned short*)d_ws;        // 2M u16
  unsigned short* k_  = q_  + (size_t)2097152;        // 4M
  unsigned short* v_  = k_  + (size_t)4194304;        // 4M
  unsigned short* r_  = v_  + (size_t)4194304;        // 1M
  unsigned short* xb  = r_  + (size_t)1048576;        // 4M
  unsigned short* pb  = xb  + (size_t)4194304;        // 1M
  unsigned short* wt  = pb  + (size_t)1048576;        // 1M
  unsigned short* woh = wt  + (size_t)1048576;        // 256K
  unsigned short* wol = woh + (size_t)262144;         // 256K
  unsigned short* aoh = wol + (size_t)262144;         // 2M
  unsigned short* aol = aoh + (size_t)2097152;        // 2M
  unsigned short* vt_ = aol + (size_t)2097152;        // 4M

  k_f32bf16<<<2048, 256, 0, stream>>>(x, xb, (B_SZ * KLEN * DM) / 8);
  k_f32bf16<<<512, 256, 0, stream>>>(p, pb, (KLEN * DM) / 8);
  k_wtrans<<<dim3(8, 8, 4), 256, 0, stream>>>(Wq, Wk, Wv, Wp, wt);
  k_wosplit<<<128, 256, 0, stream>>>(Wo, woh, wol, (DM * DM) / 8);
  k_proj_mfma<<<dim3(176, 4), 256, 0, stream>>>(xb, pb, wt, q_, k_, v_, r_);
  k_vtrans<<<dim3(KLEN / 64, NHEAD * B_SZ), 256, 0, stream>>>(v_, vt_);
  k_attn_mfma<<<dim3(16, 8, 4), 256, 0, stream>>>(
      q_, k_, vt_, r_, bk, br, aoh, aol);
  k_out_mfma<<<dim3(64, 8), 256, 0, stream>>>(aoh, aol, woh, wol, out);
}